// Round 20
// baseline (82.362 us; speedup 1.0000x reference)
//
#include <hip/hip_runtime.h>
#include <hip/hip_bf16.h>

// FactorizedTrilinear: out[b,z,x,c,dv] = sum_e p1[b,z,dv,e] p2[b,x,dv,e] p3[b,c,dv,e]
// B=4, Z=128, DV=4, IN=512, R=256. Output 4*128^3*4 fp32 = 134 MB.
// R20: R17 base (53.0 us) with ONE tri change: the per-z p1 fragment reads
// move from LDS (sP1, deleted) to GLOBAL (wave-uniform addr -> L1 broadcast,
// 2 distinct 16B lines per wave-load). LDS-pipe accounting: R17 tri = 4 blk x
// 8 z x 8 waves x (192 sP1 + 186 sT) cyc ~= 97k cyc/CU ~= 40 us = the tri
// time; u-from-global cuts the LDS pipe to ~20 us (sT only), overlapping the
// ~19.5 us store drain. pv[16]+bq[16] stay register-resident ((256,2), no
// spill tripwire = FETCH_SIZE). proj = R17 verbatim.

typedef _Float16 f16;
typedef __attribute__((ext_vector_type(8)))  _Float16 f16x8;
typedef __attribute__((ext_vector_type(4)))  float    f32x4;
typedef __attribute__((ext_vector_type(16))) float    f32x16;

// LDS-only barrier: waits local ds ops, does NOT drain global loads/stores.
__device__ __forceinline__ void lds_barrier() {
    __builtin_amdgcn_sched_barrier(0);
    asm volatile("s_waitcnt lgkmcnt(0)" ::: "memory");
    __builtin_amdgcn_s_barrier();
    __builtin_amdgcn_sched_barrier(0);
}

// ---------------- Stage 1: projections via 32x32x16 f16 MFMA (R17 verbatim) ----------------
// Block 128 thr = 2 waves (m-split) -> tile 64m x 32n; grid (32,8,3) = 768
// blocks = 3/CU exact. 16 chunks, dbuf sWt, reg prefetch, lgkm-only barrier.
__global__ __launch_bounds__(128) void proj_kernel(
    const float* __restrict__ x1, const float* __restrict__ x2, const float* __restrict__ x3,
    const float* __restrict__ W1, const float* __restrict__ b1,
    const float* __restrict__ W2, const float* __restrict__ b2,
    const float* __restrict__ W3, const float* __restrict__ b3,
    f16* __restrict__ p1, f16* __restrict__ p2, f16* __restrict__ p3) {
    const int mat = blockIdx.z;
    const float* __restrict__ x    = (mat == 0) ? x1 : (mat == 1) ? x2 : x3;
    const float* __restrict__ W    = (mat == 0) ? W1 : (mat == 1) ? W2 : W3;
    const float* __restrict__ bias = (mat == 0) ? b1 : (mat == 1) ? b2 : b3;
    f16* __restrict__ p = (mat == 0) ? p1 : (mat == 1) ? p2 : p3;

    const int tid  = threadIdx.x;
    const int lane = tid & 63;
    const int w    = tid >> 6;          // wave = m-half
    const int ln   = lane & 31;
    const int kq   = lane >> 5;
    const int m0   = blockIdx.x * 64 + w * 32;
    const int n0b  = blockIdx.y * 32;

    __shared__ f16 sWt[2][32 * 40];     // dbuf [n][k], stride 40 f16

    f32x16 acc;
#pragma unroll
    for (int i = 0; i < 16; ++i) acc[i] = 0.f;

    const int snn = tid & 31, skk0 = tid >> 5;
    const float* Xr = x + (size_t)(m0 + ln) * 512 + kq * 8;

    float wr[8], wr2[8];
    f32x4 xr[4], xn[4];
#pragma unroll
    for (int j = 0; j < 8; ++j)
        wr[j] = W[(size_t)(skk0 + 4 * j) * 256 + n0b + snn];
#pragma unroll
    for (int t = 0; t < 2; ++t) {
        xr[2 * t]     = *(const f32x4*)(Xr + t * 16);
        xr[2 * t + 1] = *(const f32x4*)(Xr + t * 16 + 4);
    }

#pragma unroll 1
    for (int ch = 0; ch < 16; ++ch) {
        const int buf = ch & 1;
#pragma unroll
        for (int j = 0; j < 8; ++j)
            sWt[buf][snn * 40 + skk0 + 4 * j] = (f16)wr[j];
        if (ch < 15) {
            const int k1 = (ch + 1) * 32;
#pragma unroll
            for (int j = 0; j < 8; ++j)
                wr2[j] = W[(size_t)(k1 + skk0 + 4 * j) * 256 + n0b + snn];
#pragma unroll
            for (int t = 0; t < 2; ++t) {
                xn[2 * t]     = *(const f32x4*)(Xr + k1 + t * 16);
                xn[2 * t + 1] = *(const f32x4*)(Xr + k1 + t * 16 + 4);
            }
        }
        lds_barrier();
#pragma unroll
        for (int ks = 0; ks < 2; ++ks) {
            f32x4 a0 = xr[2 * ks], a1 = xr[2 * ks + 1];
            f16x8 av;
            av[0] = (f16)a0[0]; av[1] = (f16)a0[1]; av[2] = (f16)a0[2]; av[3] = (f16)a0[3];
            av[4] = (f16)a1[0]; av[5] = (f16)a1[1]; av[6] = (f16)a1[2]; av[7] = (f16)a1[3];
            f16x8 bv = *(const f16x8*)&sWt[buf][ln * 40 + ks * 16 + kq * 8];
            acc = __builtin_amdgcn_mfma_f32_32x32x16_f16(av, bv, acc, 0, 0, 0);
        }
#pragma unroll
        for (int t = 0; t < 4; ++t) xr[t] = xn[t];
#pragma unroll
        for (int j = 0; j < 8; ++j) wr[j] = wr2[j];
    }

    const int n = n0b + ln;
    const float bn = bias[n];
#pragma unroll
    for (int i = 0; i < 16; ++i) {
        const int m  = m0 + (i & 3) + 8 * (i >> 2) + 4 * kq;
        const int bb = m >> 9, z = (m >> 2) & 127, dv = m & 3;
        p[((bb * 4 + dv) * 128 + z) * 256 + n] = (f16)(acc[i] + bn);
    }
}

// ---------------- Stage 2: trilinear, u-from-global + LDS transpose ----------------
// Grid = b(4) x xt(4) x ct(4) x zg(16) = 1024 blocks; 256 thr = 4 waves,
// wave w = dv. Wave: 32x x 32c x 8z x 1dv.
// pv[16] (p2 x-rows), bq[16] (p3 c-rows): full K=256 in 128 VGPRs, z-invariant.
// u (p1 z-row) read per-ks from GLOBAL (uniform -> L1 broadcast; vector-mem
// pipe, not LDS pipe). Per z: 16 MFMA -> sT[zi&1][dv][x][c] (stride 33) ->
// lgkm-only barrier -> transposed f32x4-over-dv PLAIN stores.
__global__ __launch_bounds__(256, 2) void tri_kernel(
    const f16* __restrict__ p1, const f16* __restrict__ p2,
    const f16* __restrict__ p3, float* __restrict__ out) {
    const int bi = blockIdx.x;
    const int zg = bi & 15;
    const int ct = (bi >> 4) & 3;
    const int xt = (bi >> 6) & 3;
    const int b  = bi >> 8;

    const int tid  = threadIdx.x;
    const int lane = tid & 63;
    const int w    = tid >> 6;          // = dv
    const int ln   = lane & 31;
    const int kq   = lane >> 5;
    const int x0   = xt * 32;
    const int c0   = ct * 32;
    const int z0   = zg * 8;
    const int sl   = b * 4 + w;

    __shared__ float sT[2][4 * 32 * 33];   // 2 x 16.5 KB transpose buffers

    // ---- prologue: full-K fragments in registers (z-invariant) ----
    f16x8 pv[16], bq[16];
    const f16* P2r = p2 + ((sl * 128 + x0 + ln) << 8) + kq * 8;
    const f16* P3r = p3 + ((sl * 128 + c0 + ln) << 8) + kq * 8;
#pragma unroll
    for (int ks = 0; ks < 16; ++ks) {
        pv[ks] = *(const f16x8*)(P2r + ks * 16);
        bq[ks] = *(const f16x8*)(P3r + ks * 16);
    }
    const f16* P1r = p1 + ((sl * 128 + z0) << 8) + kq * 8;   // +256 per z

    const int cl = tid & 31, xg = tid >> 5;

#pragma unroll 1
    for (int zi = 0; zi < 8; ++zi) {
        f32x16 acc;
#pragma unroll
        for (int i = 0; i < 16; ++i) acc[i] = 0.f;

#pragma unroll
        for (int ks = 0; ks < 16; ++ks) {
            f16x8 u  = *(const f16x8*)(P1r + zi * 256 + ks * 16);  // uniform -> L1 bcast
            f16x8 af = u * pv[ks];        // 4x v_pk_mul_f16
            acc = __builtin_amdgcn_mfma_f32_32x32x16_f16(af, bq[ks], acc, 0, 0, 0);
        }

        // ---- acc -> LDS sT[zi&1][dv][x][c] (stride 33: conflict-free) ----
        float* T = sT[zi & 1];
#pragma unroll
        for (int i = 0; i < 16; ++i) {
            const int xl = (i & 3) + 8 * (i >> 2) + 4 * kq;
            T[w * 1056 + xl * 33 + ln] = acc[i];
        }
        lds_barrier();   // lgkm only: stores from prior iters keep draining

        // ---- transposed read + coalesced f32x4-over-dv PLAIN stores ----
        const int z = z0 + zi;
#pragma unroll
        for (int j = 0; j < 4; ++j) {
            const int xl = xg * 4 + j;
            f32x4 v;
            v[0] = T[0 * 1056 + xl * 33 + cl];
            v[1] = T[1 * 1056 + xl * 33 + cl];
            v[2] = T[2 * 1056 + xl * 33 + cl];
            v[3] = T[3 * 1056 + xl * 33 + cl];
            const size_t idx = (size_t)((b * 128 + z) * 128 + x0 + xl) * 128 + c0 + cl;
            *(f32x4*)(out + idx * 4) = v;   // plain store: L2 write-back path
        }
        // no second barrier: next iter writes the other sT buffer.
    }
}

extern "C" void kernel_launch(void* const* d_in, const int* in_sizes, int n_in,
                              void* d_out, int out_size, void* d_ws, size_t ws_size,
                              hipStream_t stream) {
    const float* x1 = (const float*)d_in[0];
    const float* x2 = (const float*)d_in[1];
    const float* x3 = (const float*)d_in[2];
    const float* W1 = (const float*)d_in[3];
    const float* b1 = (const float*)d_in[4];
    const float* W2 = (const float*)d_in[5];
    const float* b2 = (const float*)d_in[6];
    const float* W3 = (const float*)d_in[7];
    const float* b3 = (const float*)d_in[8];

    char* ws = (char*)d_ws;
    f16* p1 = (f16*)ws;                            // [16][128][256] f16 = 1 MB
    f16* p2 = (f16*)(ws + (1u << 20));             // 1 MB
    f16* p3 = (f16*)(ws + 2u * (1u << 20));        // 1 MB

    proj_kernel<<<dim3(32, 8, 3), 128, 0, stream>>>(x1, x2, x3, W1, b1, W2, b2, W3, b3,
                                                    p1, p2, p3);
    tri_kernel<<<dim3(1024), 256, 0, stream>>>(p1, p2, p3, (float*)d_out);
}

// Round 21
// 60.647 us; speedup vs baseline: 1.3581x; 1.3581x over previous
//
#include <hip/hip_runtime.h>
#include <hip/hip_bf16.h>

// FactorizedTrilinear: out[b,z,x,c,dv] = sum_e p1[b,z,dv,e] p2[b,x,dv,e] p3[b,c,dv,e]
// B=4, Z=128, DV=4, IN=512, R=256. Output 4*128^3*4 fp32 = 134 MB.
// R21: R17 base (best, 53.0 us) with ONE change: zg split 16 -> 32 (4 z-iters
// per block), grid 1024 -> 2048 blocks. Shorter blocks + 3 resident/CU (LDS
// 41 KB) let different blocks' prologue / compute / store phases interleave.
// [R20 lesson: u MUST stay LDS-staged — per-ks uniform global loads cost ~30us
// (explains R10/R12/R20). Fragment reload traffic doubles but is L2-absorbed.]

typedef _Float16 f16;
typedef __attribute__((ext_vector_type(8)))  _Float16 f16x8;
typedef __attribute__((ext_vector_type(4)))  float    f32x4;
typedef __attribute__((ext_vector_type(16))) float    f32x16;

// LDS-only barrier: waits local ds ops, does NOT drain global loads/stores.
__device__ __forceinline__ void lds_barrier() {
    __builtin_amdgcn_sched_barrier(0);
    asm volatile("s_waitcnt lgkmcnt(0)" ::: "memory");
    __builtin_amdgcn_s_barrier();
    __builtin_amdgcn_sched_barrier(0);
}

// ---------------- Stage 1: projections via 32x32x16 f16 MFMA (R17 verbatim) ----------------
// Block 128 thr = 2 waves (m-split) -> tile 64m x 32n; grid (32,8,3) = 768
// blocks = 3/CU exact. 16 chunks, dbuf sWt, reg prefetch, lgkm-only barrier.
__global__ __launch_bounds__(128) void proj_kernel(
    const float* __restrict__ x1, const float* __restrict__ x2, const float* __restrict__ x3,
    const float* __restrict__ W1, const float* __restrict__ b1,
    const float* __restrict__ W2, const float* __restrict__ b2,
    const float* __restrict__ W3, const float* __restrict__ b3,
    f16* __restrict__ p1, f16* __restrict__ p2, f16* __restrict__ p3) {
    const int mat = blockIdx.z;
    const float* __restrict__ x    = (mat == 0) ? x1 : (mat == 1) ? x2 : x3;
    const float* __restrict__ W    = (mat == 0) ? W1 : (mat == 1) ? W2 : W3;
    const float* __restrict__ bias = (mat == 0) ? b1 : (mat == 1) ? b2 : b3;
    f16* __restrict__ p = (mat == 0) ? p1 : (mat == 1) ? p2 : p3;

    const int tid  = threadIdx.x;
    const int lane = tid & 63;
    const int w    = tid >> 6;          // wave = m-half
    const int ln   = lane & 31;
    const int kq   = lane >> 5;
    const int m0   = blockIdx.x * 64 + w * 32;
    const int n0b  = blockIdx.y * 32;

    __shared__ f16 sWt[2][32 * 40];     // dbuf [n][k], stride 40 f16

    f32x16 acc;
#pragma unroll
    for (int i = 0; i < 16; ++i) acc[i] = 0.f;

    const int snn = tid & 31, skk0 = tid >> 5;
    const float* Xr = x + (size_t)(m0 + ln) * 512 + kq * 8;

    float wr[8], wr2[8];
    f32x4 xr[4], xn[4];
#pragma unroll
    for (int j = 0; j < 8; ++j)
        wr[j] = W[(size_t)(skk0 + 4 * j) * 256 + n0b + snn];
#pragma unroll
    for (int t = 0; t < 2; ++t) {
        xr[2 * t]     = *(const f32x4*)(Xr + t * 16);
        xr[2 * t + 1] = *(const f32x4*)(Xr + t * 16 + 4);
    }

#pragma unroll 1
    for (int ch = 0; ch < 16; ++ch) {
        const int buf = ch & 1;
#pragma unroll
        for (int j = 0; j < 8; ++j)
            sWt[buf][snn * 40 + skk0 + 4 * j] = (f16)wr[j];
        if (ch < 15) {
            const int k1 = (ch + 1) * 32;
#pragma unroll
            for (int j = 0; j < 8; ++j)
                wr2[j] = W[(size_t)(k1 + skk0 + 4 * j) * 256 + n0b + snn];
#pragma unroll
            for (int t = 0; t < 2; ++t) {
                xn[2 * t]     = *(const f32x4*)(Xr + k1 + t * 16);
                xn[2 * t + 1] = *(const f32x4*)(Xr + k1 + t * 16 + 4);
            }
        }
        lds_barrier();
#pragma unroll
        for (int ks = 0; ks < 2; ++ks) {
            f32x4 a0 = xr[2 * ks], a1 = xr[2 * ks + 1];
            f16x8 av;
            av[0] = (f16)a0[0]; av[1] = (f16)a0[1]; av[2] = (f16)a0[2]; av[3] = (f16)a0[3];
            av[4] = (f16)a1[0]; av[5] = (f16)a1[1]; av[6] = (f16)a1[2]; av[7] = (f16)a1[3];
            f16x8 bv = *(const f16x8*)&sWt[buf][ln * 40 + ks * 16 + kq * 8];
            acc = __builtin_amdgcn_mfma_f32_32x32x16_f16(av, bv, acc, 0, 0, 0);
        }
#pragma unroll
        for (int t = 0; t < 4; ++t) xr[t] = xn[t];
#pragma unroll
        for (int j = 0; j < 8; ++j) wr[j] = wr2[j];
    }

    const int n = n0b + ln;
    const float bn = bias[n];
#pragma unroll
    for (int i = 0; i < 16; ++i) {
        const int m  = m0 + (i & 3) + 8 * (i >> 2) + 4 * kq;
        const int bb = m >> 9, z = (m >> 2) & 127, dv = m & 3;
        p[((bb * 4 + dv) * 128 + z) * 256 + n] = (f16)(acc[i] + bn);
    }
}

// ---------------- Stage 2: trilinear (R17 structure, 4 z per block) ----------------
// Grid = b(4) x xt(4) x ct(4) x zg(32), zg fastest = 2048 blocks; 256 thr =
// 4 waves, wave w = dv. Wave: 32x x 32c x 4z x 1dv.
// pv[16] (p2 x-rows), bq[16] (p3 c-rows): full K=256 in 128 VGPRs, z-invariant.
// p1 z-rows staged in wave-private sP1 (8 KB). Per z: 16 MFMA ->
// sT[zi&1][dv][x][c] (stride 33) -> lgkm-only barrier -> transposed
// f32x4-over-dv PLAIN stores. LDS 41 KB -> 3 blocks/CU.
__global__ __launch_bounds__(256, 2) void tri_kernel(
    const f16* __restrict__ p1, const f16* __restrict__ p2,
    const f16* __restrict__ p3, float* __restrict__ out) {
    const int bi = blockIdx.x;
    const int zg = bi & 31;
    const int ct = (bi >> 5) & 3;
    const int xt = (bi >> 7) & 3;
    const int b  = bi >> 9;

    const int tid  = threadIdx.x;
    const int lane = tid & 63;
    const int w    = tid >> 6;          // = dv
    const int ln   = lane & 31;
    const int kq   = lane >> 5;
    const int x0   = xt * 32;
    const int c0   = ct * 32;
    const int z0   = zg * 4;
    const int sl   = b * 4 + w;

    __shared__ __align__(16) f16  sP1[4][4 * 256];   // 8 KB, wave-private p1 rows
    __shared__ float sT[2][4 * 32 * 33];             // 2 x 16.5 KB transpose buffers

    // ---- stage this wave's 4 p1 z-rows (wave-private: no barrier) ----
#pragma unroll
    for (int i = 0; i < 2; ++i) {
        const int G  = i * 64 + lane;
        const int zo = G >> 5, es = G & 31;
        f16x8 v = *(const f16x8*)(p1 + ((sl * 128 + z0 + zo) << 8) + es * 8);
        *(f16x8*)&sP1[w][G * 8] = v;
    }

    // ---- prologue: full-K fragments in registers (z-invariant) ----
    f16x8 pv[16], bq[16];
    const f16* P2r = p2 + ((sl * 128 + x0 + ln) << 8) + kq * 8;
    const f16* P3r = p3 + ((sl * 128 + c0 + ln) << 8) + kq * 8;
#pragma unroll
    for (int ks = 0; ks < 16; ++ks) {
        pv[ks] = *(const f16x8*)(P2r + ks * 16);
        bq[ks] = *(const f16x8*)(P3r + ks * 16);
    }

    const int cl = tid & 31, xg = tid >> 5;

#pragma unroll 1
    for (int zi = 0; zi < 4; ++zi) {
        f32x16 acc;
#pragma unroll
        for (int i = 0; i < 16; ++i) acc[i] = 0.f;

#pragma unroll
        for (int ks = 0; ks < 16; ++ks) {
            f16x8 u = *(const f16x8*)&sP1[w][(zi * 32 + ks * 2 + kq) * 8];  // broadcast
            f16x8 af = u * pv[ks];        // 4x v_pk_mul_f16
            acc = __builtin_amdgcn_mfma_f32_32x32x16_f16(af, bq[ks], acc, 0, 0, 0);
        }

        // ---- acc -> LDS sT[zi&1][dv][x][c] (stride 33: conflict-free) ----
        float* T = sT[zi & 1];
#pragma unroll
        for (int i = 0; i < 16; ++i) {
            const int xl = (i & 3) + 8 * (i >> 2) + 4 * kq;
            T[w * 1056 + xl * 33 + ln] = acc[i];
        }
        lds_barrier();   // lgkm only: stores from prior iters keep draining

        // ---- transposed read + coalesced f32x4-over-dv PLAIN stores ----
        const int z = z0 + zi;
#pragma unroll
        for (int j = 0; j < 4; ++j) {
            const int xl = xg * 4 + j;
            f32x4 v;
            v[0] = T[0 * 1056 + xl * 33 + cl];
            v[1] = T[1 * 1056 + xl * 33 + cl];
            v[2] = T[2 * 1056 + xl * 33 + cl];
            v[3] = T[3 * 1056 + xl * 33 + cl];
            const size_t idx = (size_t)((b * 128 + z) * 128 + x0 + xl) * 128 + c0 + cl;
            *(f32x4*)(out + idx * 4) = v;   // plain store: L2 write-back path
        }
        // no second barrier: next iter writes the other sT buffer.
    }
}

extern "C" void kernel_launch(void* const* d_in, const int* in_sizes, int n_in,
                              void* d_out, int out_size, void* d_ws, size_t ws_size,
                              hipStream_t stream) {
    const float* x1 = (const float*)d_in[0];
    const float* x2 = (const float*)d_in[1];
    const float* x3 = (const float*)d_in[2];
    const float* W1 = (const float*)d_in[3];
    const float* b1 = (const float*)d_in[4];
    const float* W2 = (const float*)d_in[5];
    const float* b2 = (const float*)d_in[6];
    const float* W3 = (const float*)d_in[7];
    const float* b3 = (const float*)d_in[8];

    char* ws = (char*)d_ws;
    f16* p1 = (f16*)ws;                            // [16][128][256] f16 = 1 MB
    f16* p2 = (f16*)(ws + (1u << 20));             // 1 MB
    f16* p3 = (f16*)(ws + 2u * (1u << 20));        // 1 MB

    proj_kernel<<<dim3(32, 8, 3), 128, 0, stream>>>(x1, x2, x3, W1, b1, W2, b2, W3, b3,
                                                    p1, p2, p3);
    tri_kernel<<<dim3(2048), 256, 0, stream>>>(p1, p2, p3, (float*)d_out);
}

// Round 22
// 51.573 us; speedup vs baseline: 1.5970x; 1.1759x over previous
//
#include <hip/hip_runtime.h>
#include <hip/hip_bf16.h>

// FactorizedTrilinear: out[b,z,x,c,dv] = sum_e p1[b,z,dv,e] p2[b,x,dv,e] p3[b,c,dv,e]
// B=4, Z=128, DV=4, IN=512, R=256. Output 4*128^3*4 fp32 = 134 MB.
// R22: R17 base (best, 53.0) with ONE change, the R21-INVERSE: zg 16 -> 8
// (16 z per block), grid 1024 -> 512 = exactly 2 resident blocks/CU (LDS
// 65 KB). Eliminates R17's 256-block tail round (1 block/CU, zero overlap)
// and halves per-block prologue traffic. [R21: smaller blocks = worse (+7.6);
// R20: u must stay LDS-staged; R12: wave count neutral; R13: plain > NT.]

typedef _Float16 f16;
typedef __attribute__((ext_vector_type(8)))  _Float16 f16x8;
typedef __attribute__((ext_vector_type(4)))  float    f32x4;
typedef __attribute__((ext_vector_type(16))) float    f32x16;

// LDS-only barrier: waits local ds ops, does NOT drain global loads/stores.
__device__ __forceinline__ void lds_barrier() {
    __builtin_amdgcn_sched_barrier(0);
    asm volatile("s_waitcnt lgkmcnt(0)" ::: "memory");
    __builtin_amdgcn_s_barrier();
    __builtin_amdgcn_sched_barrier(0);
}

// ---------------- Stage 1: projections via 32x32x16 f16 MFMA (R17 verbatim) ----------------
// Block 128 thr = 2 waves (m-split) -> tile 64m x 32n; grid (32,8,3) = 768
// blocks = 3/CU exact. 16 chunks, dbuf sWt, reg prefetch, lgkm-only barrier.
__global__ __launch_bounds__(128) void proj_kernel(
    const float* __restrict__ x1, const float* __restrict__ x2, const float* __restrict__ x3,
    const float* __restrict__ W1, const float* __restrict__ b1,
    const float* __restrict__ W2, const float* __restrict__ b2,
    const float* __restrict__ W3, const float* __restrict__ b3,
    f16* __restrict__ p1, f16* __restrict__ p2, f16* __restrict__ p3) {
    const int mat = blockIdx.z;
    const float* __restrict__ x    = (mat == 0) ? x1 : (mat == 1) ? x2 : x3;
    const float* __restrict__ W    = (mat == 0) ? W1 : (mat == 1) ? W2 : W3;
    const float* __restrict__ bias = (mat == 0) ? b1 : (mat == 1) ? b2 : b3;
    f16* __restrict__ p = (mat == 0) ? p1 : (mat == 1) ? p2 : p3;

    const int tid  = threadIdx.x;
    const int lane = tid & 63;
    const int w    = tid >> 6;          // wave = m-half
    const int ln   = lane & 31;
    const int kq   = lane >> 5;
    const int m0   = blockIdx.x * 64 + w * 32;
    const int n0b  = blockIdx.y * 32;

    __shared__ f16 sWt[2][32 * 40];     // dbuf [n][k], stride 40 f16

    f32x16 acc;
#pragma unroll
    for (int i = 0; i < 16; ++i) acc[i] = 0.f;

    const int snn = tid & 31, skk0 = tid >> 5;
    const float* Xr = x + (size_t)(m0 + ln) * 512 + kq * 8;

    float wr[8], wr2[8];
    f32x4 xr[4], xn[4];
#pragma unroll
    for (int j = 0; j < 8; ++j)
        wr[j] = W[(size_t)(skk0 + 4 * j) * 256 + n0b + snn];
#pragma unroll
    for (int t = 0; t < 2; ++t) {
        xr[2 * t]     = *(const f32x4*)(Xr + t * 16);
        xr[2 * t + 1] = *(const f32x4*)(Xr + t * 16 + 4);
    }

#pragma unroll 1
    for (int ch = 0; ch < 16; ++ch) {
        const int buf = ch & 1;
#pragma unroll
        for (int j = 0; j < 8; ++j)
            sWt[buf][snn * 40 + skk0 + 4 * j] = (f16)wr[j];
        if (ch < 15) {
            const int k1 = (ch + 1) * 32;
#pragma unroll
            for (int j = 0; j < 8; ++j)
                wr2[j] = W[(size_t)(k1 + skk0 + 4 * j) * 256 + n0b + snn];
#pragma unroll
            for (int t = 0; t < 2; ++t) {
                xn[2 * t]     = *(const f32x4*)(Xr + k1 + t * 16);
                xn[2 * t + 1] = *(const f32x4*)(Xr + k1 + t * 16 + 4);
            }
        }
        lds_barrier();
#pragma unroll
        for (int ks = 0; ks < 2; ++ks) {
            f32x4 a0 = xr[2 * ks], a1 = xr[2 * ks + 1];
            f16x8 av;
            av[0] = (f16)a0[0]; av[1] = (f16)a0[1]; av[2] = (f16)a0[2]; av[3] = (f16)a0[3];
            av[4] = (f16)a1[0]; av[5] = (f16)a1[1]; av[6] = (f16)a1[2]; av[7] = (f16)a1[3];
            f16x8 bv = *(const f16x8*)&sWt[buf][ln * 40 + ks * 16 + kq * 8];
            acc = __builtin_amdgcn_mfma_f32_32x32x16_f16(av, bv, acc, 0, 0, 0);
        }
#pragma unroll
        for (int t = 0; t < 4; ++t) xr[t] = xn[t];
#pragma unroll
        for (int j = 0; j < 8; ++j) wr[j] = wr2[j];
    }

    const int n = n0b + ln;
    const float bn = bias[n];
#pragma unroll
    for (int i = 0; i < 16; ++i) {
        const int m  = m0 + (i & 3) + 8 * (i >> 2) + 4 * kq;
        const int bb = m >> 9, z = (m >> 2) & 127, dv = m & 3;
        p[((bb * 4 + dv) * 128 + z) * 256 + n] = (f16)(acc[i] + bn);
    }
}

// ---------------- Stage 2: trilinear (R17 structure, 16 z per block) ----------------
// Grid = b(4) x xt(4) x ct(4) x zg(8), zg fastest = 512 blocks = 2/CU exact;
// 256 thr = 4 waves, wave w = dv. Wave: 32x x 32c x 16z x 1dv.
// pv[16] (p2 x-rows), bq[16] (p3 c-rows): full K=256 in 128 VGPRs, z-invariant.
// p1 z-rows staged in wave-private sP1 (32 KB). Per z: 16 MFMA ->
// sT[zi&1][dv][x][c] (stride 33) -> lgkm-only barrier -> transposed
// f32x4-over-dv PLAIN stores. LDS 65 KB -> 2 blocks/CU, one round, no tail.
__global__ __launch_bounds__(256, 2) void tri_kernel(
    const f16* __restrict__ p1, const f16* __restrict__ p2,
    const f16* __restrict__ p3, float* __restrict__ out) {
    const int bi = blockIdx.x;
    const int zg = bi & 7;
    const int ct = (bi >> 3) & 3;
    const int xt = (bi >> 5) & 3;
    const int b  = bi >> 7;

    const int tid  = threadIdx.x;
    const int lane = tid & 63;
    const int w    = tid >> 6;          // = dv
    const int ln   = lane & 31;
    const int kq   = lane >> 5;
    const int x0   = xt * 32;
    const int c0   = ct * 32;
    const int z0   = zg * 16;
    const int sl   = b * 4 + w;

    __shared__ __align__(16) f16  sP1[4][16 * 256];  // 32 KB, wave-private p1 rows
    __shared__ float sT[2][4 * 32 * 33];             // 2 x 16.5 KB transpose buffers

    // ---- stage this wave's 16 p1 z-rows (wave-private: no barrier) ----
#pragma unroll
    for (int i = 0; i < 8; ++i) {
        const int G  = i * 64 + lane;
        const int zo = G >> 5, es = G & 31;
        f16x8 v = *(const f16x8*)(p1 + ((sl * 128 + z0 + zo) << 8) + es * 8);
        *(f16x8*)&sP1[w][G * 8] = v;
    }

    // ---- prologue: full-K fragments in registers (z-invariant) ----
    f16x8 pv[16], bq[16];
    const f16* P2r = p2 + ((sl * 128 + x0 + ln) << 8) + kq * 8;
    const f16* P3r = p3 + ((sl * 128 + c0 + ln) << 8) + kq * 8;
#pragma unroll
    for (int ks = 0; ks < 16; ++ks) {
        pv[ks] = *(const f16x8*)(P2r + ks * 16);
        bq[ks] = *(const f16x8*)(P3r + ks * 16);
    }

    const int cl = tid & 31, xg = tid >> 5;

#pragma unroll 1
    for (int zi = 0; zi < 16; ++zi) {
        f32x16 acc;
#pragma unroll
        for (int i = 0; i < 16; ++i) acc[i] = 0.f;

#pragma unroll
        for (int ks = 0; ks < 16; ++ks) {
            f16x8 u = *(const f16x8*)&sP1[w][(zi * 32 + ks * 2 + kq) * 8];  // broadcast
            f16x8 af = u * pv[ks];        // 4x v_pk_mul_f16
            acc = __builtin_amdgcn_mfma_f32_32x32x16_f16(af, bq[ks], acc, 0, 0, 0);
        }

        // ---- acc -> LDS sT[zi&1][dv][x][c] (stride 33: conflict-free) ----
        float* T = sT[zi & 1];
#pragma unroll
        for (int i = 0; i < 16; ++i) {
            const int xl = (i & 3) + 8 * (i >> 2) + 4 * kq;
            T[w * 1056 + xl * 33 + ln] = acc[i];
        }
        lds_barrier();   // lgkm only: stores from prior iters keep draining

        // ---- transposed read + coalesced f32x4-over-dv PLAIN stores ----
        const int z = z0 + zi;
#pragma unroll
        for (int j = 0; j < 4; ++j) {
            const int xl = xg * 4 + j;
            f32x4 v;
            v[0] = T[0 * 1056 + xl * 33 + cl];
            v[1] = T[1 * 1056 + xl * 33 + cl];
            v[2] = T[2 * 1056 + xl * 33 + cl];
            v[3] = T[3 * 1056 + xl * 33 + cl];
            const size_t idx = (size_t)((b * 128 + z) * 128 + x0 + xl) * 128 + c0 + cl;
            *(f32x4*)(out + idx * 4) = v;   // plain store: L2 write-back path
        }
        // no second barrier: next iter writes the other sT buffer.
    }
}

extern "C" void kernel_launch(void* const* d_in, const int* in_sizes, int n_in,
                              void* d_out, int out_size, void* d_ws, size_t ws_size,
                              hipStream_t stream) {
    const float* x1 = (const float*)d_in[0];
    const float* x2 = (const float*)d_in[1];
    const float* x3 = (const float*)d_in[2];
    const float* W1 = (const float*)d_in[3];
    const float* b1 = (const float*)d_in[4];
    const float* W2 = (const float*)d_in[5];
    const float* b2 = (const float*)d_in[6];
    const float* W3 = (const float*)d_in[7];
    const float* b3 = (const float*)d_in[8];

    char* ws = (char*)d_ws;
    f16* p1 = (f16*)ws;                            // [16][128][256] f16 = 1 MB
    f16* p2 = (f16*)(ws + (1u << 20));             // 1 MB
    f16* p3 = (f16*)(ws + 2u * (1u << 20));        // 1 MB

    proj_kernel<<<dim3(32, 8, 3), 128, 0, stream>>>(x1, x2, x3, W1, b1, W2, b2, W3, b3,
                                                    p1, p2, p3);
    tri_kernel<<<dim3(512), 256, 0, stream>>>(p1, p2, p3, (float*)d_out);
}